// Round 19
// baseline (494.121 us; speedup 1.0000x reference)
//
#include <hip/hip_runtime.h>
#include <stdint.h>

#define D 2048
#define R 64
#define M_TOTAL 8192

typedef float f32x4 __attribute__((ext_vector_type(4)));
typedef __bf16 bf16x8 __attribute__((ext_vector_type(8)));
typedef unsigned short u16x8 __attribute__((ext_vector_type(8)));
typedef unsigned short u16x4 __attribute__((ext_vector_type(4)));

__device__ __forceinline__ unsigned short f2bf(float f) {
  unsigned u = __builtin_bit_cast(unsigned, f);
  u += 0x7FFFu + ((u >> 16) & 1u);
  return (unsigned short)(u >> 16);
}

__device__ __forceinline__ u16x8 pack8(float4 a, float4 b) {
  u16x8 o = { f2bf(a.x), f2bf(a.y), f2bf(a.z), f2bf(a.w),
              f2bf(b.x), f2bf(b.y), f2bf(b.z), f2bf(b.w) };
  return o;
}

// Inline-asm global->LDS staging (untracked by compiler hazard pass).
// M0 = wave-uniform LDS byte base; HW writes base + lane*16.
__device__ __forceinline__ void gload_lds_asm(const unsigned short* g, int lds_byte) {
  asm volatile("s_mov_b32 m0, %1\n\t"
               "global_load_lds_dwordx4 %0, off"
               :: "v"(g), "s"(lds_byte)
               : "memory");
}
__device__ __forceinline__ u16x8 dsread_b128(int addr) {
  u16x8 r;
  asm volatile("ds_read_b128 %0, %1" : "=v"(r) : "v"(addr) : "memory");
  return r;
}
__device__ __forceinline__ int lds_addr(const void* p) {
  return (int)(size_t)(const __attribute__((address_space(3))) void*)p;
}

// ---------------- fused prep (512 threads/block) ---------------- (unchanged)
__global__ __launch_bounds__(512) void prep_kernel(
    const float* __restrict__ x, const float* __restrict__ A,
    const float* __restrict__ B, const float* __restrict__ C,
    const float* __restrict__ w1, const float* __restrict__ b1,
    const float* __restrict__ w2,
    unsigned short* __restrict__ xbf, unsigned short* __restrict__ st,
    unsigned short* __restrict__ w2bf, unsigned short* __restrict__ hbf) {
  __shared__ unsigned short plds[24576];  // 48 KB shared by roles
  const int t = threadIdx.x;
  const int bx = blockIdx.x;

  if (bx < 256) {
    unsigned short* sX = plds;
    unsigned short* sW = plds + 8192;
    const int m0 = bx * 32;
    const int kq = t >> 7, u = t & 127;
    const int row = u >> 2, c = u & 3;
    const int row_w = u >> 1, cw0 = (u & 1) * 2;
    const float* xp = x + (size_t)(m0 + row) * D + kq * 512 + c * 8;
    const float* wp = w1 + (size_t)row_w * D + kq * 512 + cw0 * 8;
    unsigned short* xw = xbf + (size_t)(m0 + row) * D + kq * 512 + c * 8;
    unsigned short* sXw = sX + kq * 2048 + row * 32 + (c ^ ((row >> 1) & 3)) * 8;
    const int rw2 = (row_w >> 1) & 3;
    unsigned short* sWw0 = sW + kq * 4096 + row_w * 32 + (cw0 ^ rw2) * 8;
    unsigned short* sWw1 = sW + kq * 4096 + row_w * 32 + ((cw0 + 1) ^ rw2) * 8;
    const int w = t >> 6, l = t & 63, lm = l & 15, lk = l >> 4;
    const int kqw = w >> 1, rg = w & 1;
    const int rslot = (lk ^ ((lm >> 1) & 3)) * 8;
    const unsigned short* sXr = sX + kqw * 2048 + (rg * 16 + lm) * 32 + rslot;
    const unsigned short* sWr = sW + kqw * 4096 + lm * 32 + rslot;

    f32x4 acc[4] = {};
    float4 qx[2][2], qw[2][4];
#define HLOADX(P, KT) do { qx[P][0] = *(const float4*)(xp + (KT) * 32); \
                           qx[P][1] = *(const float4*)(xp + (KT) * 32 + 4); } while (0)
#define HLOADW(P, KT) do { qw[P][0] = *(const float4*)(wp + (KT) * 32); \
                           qw[P][1] = *(const float4*)(wp + (KT) * 32 + 4); \
                           qw[P][2] = *(const float4*)(wp + (KT) * 32 + 8); \
                           qw[P][3] = *(const float4*)(wp + (KT) * 32 + 12); } while (0)
    HLOADX(0, 0); HLOADW(0, 0); HLOADX(1, 1); HLOADW(1, 1);
#define HSTEP(P, KT) do { \
    u16x8 ox = pack8(qx[P][0], qx[P][1]); \
    *(u16x8*)(sXw + (P) * 1024) = ox; \
    *(u16x8*)(xw + (KT) * 32) = ox; \
    *(u16x8*)(sWw0 + (P) * 2048) = pack8(qw[P][0], qw[P][1]); \
    *(u16x8*)(sWw1 + (P) * 2048) = pack8(qw[P][2], qw[P][3]); \
    if ((KT) + 2 < 16) { HLOADX(P, (KT) + 2); HLOADW(P, (KT) + 2); } \
    __syncthreads(); \
    { bf16x8 a_ = __builtin_bit_cast(bf16x8, *(const u16x8*)(sXr + (P) * 1024)); \
      _Pragma("unroll") \
      for (int j = 0; j < 4; ++j) { \
        bf16x8 b_ = __builtin_bit_cast(bf16x8, *(const u16x8*)(sWr + (P) * 2048 + j * 512)); \
        acc[j] = __builtin_amdgcn_mfma_f32_16x16x32_bf16(a_, b_, acc[j], 0, 0, 0); \
      } } } while (0)
#pragma unroll 1
    for (int it = 0; it < 8; ++it) { HSTEP(0, it * 2); HSTEP(1, it * 2 + 1); }
#undef HSTEP
#undef HLOADX
#undef HLOADW

    __syncthreads();
    float* red = (float*)plds;
    if (kqw > 0) {
#pragma unroll
      for (int j = 0; j < 4; ++j)
        *(f32x4*)(red + (((((kqw - 1) * 2 + rg) * 4) + j) * 64 + l) * 4) = acc[j];
    }
    __syncthreads();
    if (kqw == 0) {
      int m_base = m0 + rg * 16 + lk * 4;
#pragma unroll
      for (int j = 0; j < 4; ++j) {
        f32x4 s = acc[j];
#pragma unroll
        for (int q = 1; q < 4; ++q)
          s += *(const f32x4*)(red + (((((q - 1) * 2 + rg) * 4) + j) * 64 + l) * 4);
        int n = j * 16 + lm;
        float bv = b1[n];
#pragma unroll
        for (int r = 0; r < 4; ++r) {
          float v = s[r] + bv;
          float g = 0.5f * v * (1.0f + erff(v * 0.70710678118654752f));
          hbf[(size_t)(m_base + r) * R + n] = f2bf(g);
        }
      }
    }
  } else if (bx < 768) {
    unsigned short (*lds)[68] = (unsigned short(*)[68])plds;
    const int id = bx - 256;
    const int k0 = (id >> 5) * 128, n0 = (id & 31) * 64;
#pragma unroll
    for (int q = 0; q < 4; ++q) {
      int rowq = q * 32 + (t >> 4);
      int col = (t & 15) * 4;
      size_t off = (size_t)(k0 + rowq) * D + n0 + col;
      float4 a = *(const float4*)(A + off);
      float4 b = *(const float4*)(B + off);
      float4 cc = *(const float4*)(C + off);
      u16x4 o = { f2bf(a.x + b.x + cc.x), f2bf(a.y + b.y + cc.y),
                  f2bf(a.z + b.z + cc.z), f2bf(a.w + b.w + cc.w) };
      *(u16x4*)(&lds[rowq][col]) = o;
    }
    __syncthreads();
    const int n = t >> 3, kc = (t & 7) * 16;
    u16x8 v0, v1;
#pragma unroll
    for (int jj = 0; jj < 8; ++jj) v0[jj] = lds[kc + jj][n];
#pragma unroll
    for (int jj = 0; jj < 8; ++jj) v1[jj] = lds[kc + 8 + jj][n];
    size_t ooff = (size_t)(n0 + n) * D + k0 + kc;
    *(u16x8*)(st + ooff) = v0;
    *(u16x8*)(st + ooff + 8) = v1;
  } else {
    const int NW4 = (D * R) / 4;  // 32768
    for (int i = (bx - 768) * 512 + t; i < NW4; i += 4 * 512) {
      float4 v = ((const float4*)w2)[i];
      u16x4 o = { f2bf(v.x), f2bf(v.y), f2bf(v.z), f2bf(v.w) };
      *(u16x4*)(w2bf + (size_t)i * 4) = o;
    }
  }
}

// ---------------- main: out = (x @ S) * dt + Dp ----------------
// PRODUCER-CONSUMER WAVE SPECIALIZATION. 128x256 tile, BK=64, 640 threads:
// waves 0-7 = consumers (64x64 out each; per tile: 16 ds_read + lgkm +
// 32 MFMA + 1 barrier -- NO vmem, NO vmcnt, the exact V3-ablation stream
// that measured 59% MfmaUtil). Waves 8-9 = producers: ALL staging (24 asm
// global_load_lds each per tile) into a 3-slot LDS ring staged 2 tiles
// ahead; counted vmcnt(24) drains the previous tile's stage (full-tile
// issue distance) BEFORE the barrier => cross-wave visibility. LDS 144 KB.
__global__ __launch_bounds__(640, 3) void gemm_kernel(
    const unsigned short* __restrict__ xbf, const unsigned short* __restrict__ st,
    const unsigned short* __restrict__ hbf, const unsigned short* __restrict__ w2bf,
    const float* __restrict__ b2, const float* __restrict__ dp,
    float* __restrict__ out) {
  __shared__ unsigned short sA[3 * 8192];   // 3 slots x 128 rows x 64 k = 48 KB
  __shared__ unsigned short sB[3 * 16384];  // 3 slots x 256 rows x 64 k = 96 KB
  const int tid = threadIdx.x;
  const int w = tid >> 6, l = tid & 63, lk = l >> 4, lm = l & 15;
  const int wm = w >> 2, wn = w & 3;  // consumers: 2M x 4N of 64x64
  int bid = blockIdx.x;
  int wg = (bid & 7) * 64 + (bid >> 3);  // bijective XCD swizzle (512 wgs)
  int mb = wg >> 3, nb = wg & 7;         // 64 x 8
  int m0 = mb * 128, n0 = nb * 256;

  // producer per-lane global bases: chunk i covers rows i*8..i*8+7;
  // lane l -> row_off = l>>3, phys granule = l&7, logical = (l&7)^(l>>3)
  // (XOR term is lane-only because chunk row-base is a multiple of 8).
  const int kgp = (l & 7) ^ (l >> 3);
  const unsigned short* pA = xbf + (size_t)(m0 + (l >> 3)) * D + kgp * 8;
  const unsigned short* pB = st + (size_t)(n0 + (l >> 3)) * D + kgp * 8;
  const int ldsA = lds_addr(sA);
  const int ldsB = lds_addr(sB);

  // consumer read addresses: row stride 128 B; phys granule = g ^ (row&7),
  // row&7 == lm&7 for all fragments.
  const int s7 = lm & 7;
  const int gsw0 = (lk ^ s7) * 16;        // kk=0, bytes
  const int gsw1 = ((4 | lk) ^ s7) * 16;  // kk=1
  const int aRd = ldsA + (wm * 64 + lm) * 128;
  const int bRd = ldsB + (wn * 64 + lm) * 128;

  const int NT = D / 64;  // 32
  f32x4 acc[4][4] = {};

#define SB0() __builtin_amdgcn_sched_barrier(0)
#define BAR() __builtin_amdgcn_s_barrier()

// producer: stage K-tile T into slot SP (0..2). p0: A(16) + B(0..7);
// p1: B(8..31). 24 instructions each.
#define PSTAGE(T, SP) do { \
    int aD_ = ldsA + (SP) * 16384; \
    int bD_ = ldsB + (SP) * 32768; \
    if (w == 8) { \
      _Pragma("unroll") \
      for (int i = 0; i < 16; ++i) \
        gload_lds_asm(pA + (size_t)(i * 8) * D + (T) * 64, aD_ + i * 1024); \
      _Pragma("unroll") \
      for (int i = 0; i < 8; ++i) \
        gload_lds_asm(pB + (size_t)(i * 8) * D + (T) * 64, bD_ + i * 1024); \
    } else { \
      _Pragma("unroll") \
      for (int i = 8; i < 32; ++i) \
        gload_lds_asm(pB + (size_t)(i * 8) * D + (T) * 64, bD_ + i * 1024); \
    } } while (0)

#define MMH(BRR, JO) do { \
    __builtin_amdgcn_s_setprio(1); \
    _Pragma("unroll") for (int mi = 0; mi < 4; ++mi) \
    _Pragma("unroll") for (int j = 0; j < 2; ++j) { \
      acc[mi][j + JO] = __builtin_amdgcn_mfma_f32_16x16x32_bf16( \
          __builtin_bit_cast(bf16x8, aR[mi][0]), __builtin_bit_cast(bf16x8, BRR[j][0]), \
          acc[mi][j + JO], 0, 0, 0); \
      acc[mi][j + JO] = __builtin_amdgcn_mfma_f32_16x16x32_bf16( \
          __builtin_bit_cast(bf16x8, aR[mi][1]), __builtin_bit_cast(bf16x8, BRR[j][1]), \
          acc[mi][j + JO], 0, 0, 0); \
    } \
    __builtin_amdgcn_s_setprio(0); } while (0)

  // prologue: producers stage tiles 0 (slot 0) and 1 (slot 1); drain own
  // stage(0) (vmcnt(24) leaves own stage(1)); barrier -> slot 0 visible.
  if (w >= 8) {
    PSTAGE(0, 0);
    PSTAGE(1, 1);
    asm volatile("s_waitcnt vmcnt(24)" ::: "memory");
  }
  BAR();

  int sc = 0;  // consumer slot = t % 3
  int sp = 2;  // producer target slot = (t+2) % 3
#pragma unroll 1
  for (int t = 0; t < NT; ++t) {
    if (w < 8) {
      // ---- consumer: V3-shaped stream (no vmem, no vmcnt) ----
      const int aB = aRd + sc * 16384;
      const int bB = bRd + sc * 32768;
      u16x8 aR[4][2], bR[2][2];
#pragma unroll
      for (int mi = 0; mi < 4; ++mi) {
        aR[mi][0] = dsread_b128(aB + mi * 2048 + gsw0);
        aR[mi][1] = dsread_b128(aB + mi * 2048 + gsw1);
      }
#pragma unroll
      for (int j = 0; j < 2; ++j) {
        bR[j][0] = dsread_b128(bB + j * 2048 + gsw0);
        bR[j][1] = dsread_b128(bB + j * 2048 + gsw1);
      }
      SB0();
      asm volatile("s_waitcnt lgkmcnt(0)" ::: "memory");
      SB0();
      MMH(bR, 0);
      SB0();
#pragma unroll
      for (int j = 0; j < 2; ++j) {
        bR[j][0] = dsread_b128(bB + (j + 2) * 2048 + gsw0);
        bR[j][1] = dsread_b128(bB + (j + 2) * 2048 + gsw1);
      }
      SB0();
      asm volatile("s_waitcnt lgkmcnt(0)" ::: "memory");
      SB0();
      MMH(bR, 2);
      SB0();
    } else {
      // ---- producer: stage t+2; counted drain of stage(t+1) ----
      if (t + 2 < NT) {
        PSTAGE(t + 2, sp);
        asm volatile("s_waitcnt vmcnt(24)" ::: "memory");
      } else {
        asm volatile("s_waitcnt vmcnt(0)" ::: "memory");
      }
    }
    BAR();
    ++sc; if (sc == 3) sc = 0;
    ++sp; if (sp == 3) sp = 0;
  }

  // epilogue (consumers only): dt = h @ W2^T + b2, out = acc*dt + Dp
  if (w < 8) {
    bf16x8 wb0[4], wb1[4];
    float b2v[4], dpv[4];
#pragma unroll
    for (int j = 0; j < 4; ++j) {
      int n = n0 + wn * 64 + j * 16 + lm;
      const u16x8* wp = (const u16x8*)(w2bf + (size_t)n * R + lk * 8);
      wb0[j] = __builtin_bit_cast(bf16x8, wp[0]);
      wb1[j] = __builtin_bit_cast(bf16x8, wp[4]);  // +32 bf16
      b2v[j] = b2[n];
      dpv[j] = dp[n];
    }
#pragma unroll
    for (int mi = 0; mi < 4; ++mi) {
      int hrow = m0 + wm * 64 + mi * 16 + lm;
      const u16x8* hp = (const u16x8*)(hbf + (size_t)hrow * R + lk * 8);
      bf16x8 ha0 = __builtin_bit_cast(bf16x8, hp[0]);
      bf16x8 ha1 = __builtin_bit_cast(bf16x8, hp[4]);
      int mbase = m0 + wm * 64 + mi * 16 + lk * 4;
#pragma unroll
      for (int j = 0; j < 4; ++j) {
        f32x4 dt = {};
        dt = __builtin_amdgcn_mfma_f32_16x16x32_bf16(ha0, wb0[j], dt, 0, 0, 0);
        dt = __builtin_amdgcn_mfma_f32_16x16x32_bf16(ha1, wb1[j], dt, 0, 0, 0);
        int n = n0 + wn * 64 + j * 16 + lm;
#pragma unroll
        for (int r = 0; r < 4; ++r) {
          float val = acc[mi][j][r] * (dt[r] + b2v[j]) + dpv[j];
          out[(size_t)(mbase + r) * D + n] = val;
        }
      }
    }
  }
#undef MMH
#undef PSTAGE
#undef BAR
#undef SB0
}

extern "C" void kernel_launch(void* const* d_in, const int* in_sizes, int n_in,
                              void* d_out, int out_size, void* d_ws, size_t ws_size,
                              hipStream_t stream) {
  const float* x  = (const float*)d_in[0];
  const float* A  = (const float*)d_in[1];
  const float* B  = (const float*)d_in[2];
  const float* C  = (const float*)d_in[3];
  const float* Dp = (const float*)d_in[4];
  const float* W1 = (const float*)d_in[5];
  const float* b1 = (const float*)d_in[6];
  const float* W2 = (const float*)d_in[7];
  const float* b2 = (const float*)d_in[8];
  float* out = (float*)d_out;

  uint8_t* ws = (uint8_t*)d_ws;
  unsigned short* xbf  = (unsigned short*)ws;                                // 32 MB
  unsigned short* st   = (unsigned short*)(ws + (32u << 20));                // 8 MB
  unsigned short* w2bf = (unsigned short*)(ws + (40u << 20));                // 256 KB
  unsigned short* hbf  = (unsigned short*)(ws + (41u << 20));                // 1 MB

  prep_kernel<<<772, 512, 0, stream>>>(x, A, B, C, W1, b1, W2, xbf, st, w2bf, hbf);
  gemm_kernel<<<512, 640, 0, stream>>>(xbf, st, hbf, w2bf, b2, Dp, out);
}